// Round 3
// baseline (27.991 us; speedup 1.0000x reference)
//
#include <hip/hip_runtime.h>
#include <math.h>

#define MARGIN 0.2f
#define NEG_WEIGHT 0.5f

constexpr int Bc = 64, Nc = 16, Lc = 1024, DH = 64, Ac = 8;
constexpr int NSAMP = Bc * Ac;         // 512
constexpr int CHUNKS = 16;
constexpr int RPC = Lc / CHUNKS;       // 64 rows per chunk

__device__ __forceinline__ float pdist(float x2, float y2, float d2) {
    x2 = fminf(x2, 0.999999f);
    y2 = fminf(y2, 0.999999f);
    float num = 2.0f * d2;
    float den = (1.0f - x2) * (1.0f - y2);
    float ratio = num * __builtin_amdgcn_rcpf(fmaxf(den, 1e-15f));
    float z = 1.0f + fmaxf(ratio, 1.0f + 1e-7f);
    // z >= 2: acosh via log
    return __logf(z + __builtin_sqrtf(z * z - 1.0f));
}

// block = (b, no, chunk): processes rows [c*64, c*64+64) of sequence (b, no)
// ONCE, serving every sample a of batch b with n0[a]==no (dedup of duplicate reads).
// lane layout: quad = lane&3 owns 16 dims; rg = lane>>2 owns a row.
__global__ __launch_bounds__(64) void sample_kernel(
    const float* __restrict__ h_curr,
    const float* __restrict__ demo_h,
    const int*   __restrict__ align_idx,
    const int*   __restrict__ lookahead_p,
    float* __restrict__ wneg,   // [NSAMP*CHUNKS] hinge sums
    float* __restrict__ wpos)   // [NSAMP] d_pos (0 if invalid)
{
    const int blk  = blockIdx.x;
    const int c    = blk & 15;
    const int no   = (blk >> 4) & 15;
    const int b    = blk >> 8;
    const int lane = threadIdx.x;
    const int quad = lane & 3;
    const int rg   = lane >> 2;

    const int lk = lookahead_p[0];

    int  lt[Ac];
    bool m[Ac];
    bool anym = false;
    #pragma unroll
    for (int a = 0; a < Ac; ++a) {
        const int n0 = align_idx[(b * Ac + a) * 2 + 0];
        const int l0 = align_idx[(b * Ac + a) * 2 + 1];
        lt[a] = l0 + lk;
        m[a]  = (n0 == no);
        anym |= m[a];
    }
    if (!anym) return;   // wave-uniform exit

    const float* __restrict__ xrow = h_curr + (size_t)b * DH + quad * 16;
    const float* __restrict__ seq  = demo_h + (((size_t)b * Nc + (size_t)no) * Lc) * DH;

    float4 xv[4];
    #pragma unroll
    for (int j = 0; j < 4; ++j)
        xv[j] = *reinterpret_cast<const float4*>(xrow + j * 4);

    float x2 = 0.0f;
    #pragma unroll
    for (int j = 0; j < 4; ++j) {
        x2 = fmaf(xv[j].x, xv[j].x, x2); x2 = fmaf(xv[j].y, xv[j].y, x2);
        x2 = fmaf(xv[j].z, xv[j].z, x2); x2 = fmaf(xv[j].w, xv[j].w, x2);
    }
    x2 += __shfl_xor(x2, 1, 64);
    x2 += __shfl_xor(x2, 2, 64);

    // per matched+valid sample: d_pos -> margin term ma = MARGIN + d_pos
    float ma[Ac];
    bool  valid[Ac];
    #pragma unroll
    for (int a = 0; a < Ac; ++a) {
        valid[a] = m[a] && (lt[a] >= 0) && (lt[a] < Lc);
        ma[a] = 0.0f;
        if (valid[a]) {   // wave-uniform branch
            const int ltc = min(max(lt[a], 0), Lc - 1);
            const float* rowp = seq + (size_t)ltc * DH + quad * 16;
            float d2 = 0.0f, y2 = 0.0f;
            #pragma unroll
            for (int j = 0; j < 4; ++j) {
                float4 yv = *reinterpret_cast<const float4*>(rowp + j * 4);
                float dx = xv[j].x - yv.x, dy = xv[j].y - yv.y;
                float dz = xv[j].z - yv.z, dw = xv[j].w - yv.w;
                d2 = fmaf(dx, dx, d2); d2 = fmaf(dy, dy, d2);
                d2 = fmaf(dz, dz, d2); d2 = fmaf(dw, dw, d2);
                y2 = fmaf(yv.x, yv.x, y2); y2 = fmaf(yv.y, yv.y, y2);
                y2 = fmaf(yv.z, yv.z, y2); y2 = fmaf(yv.w, yv.w, y2);
            }
            d2 += __shfl_xor(d2, 1, 64); d2 += __shfl_xor(d2, 2, 64);
            y2 += __shfl_xor(y2, 1, 64); y2 += __shfl_xor(y2, 2, 64);
            ma[a] = MARGIN + pdist(x2, y2, d2);
        }
    }

    // negatives: 64 rows, read once, applied to all matched samples
    float hg[Ac];
    #pragma unroll
    for (int a = 0; a < Ac; ++a) hg[a] = 0.0f;

    #pragma unroll
    for (int it = 0; it < 4; ++it) {
        const int row = c * RPC + it * 16 + rg;
        const float* rowp = seq + (size_t)row * DH + quad * 16;
        float d2 = 0.0f, y2 = 0.0f;
        #pragma unroll
        for (int j = 0; j < 4; ++j) {
            float4 yv = *reinterpret_cast<const float4*>(rowp + j * 4);
            float dx = xv[j].x - yv.x, dy = xv[j].y - yv.y;
            float dz = xv[j].z - yv.z, dw = xv[j].w - yv.w;
            d2 = fmaf(dx, dx, d2); d2 = fmaf(dy, dy, d2);
            d2 = fmaf(dz, dz, d2); d2 = fmaf(dw, dw, d2);
            y2 = fmaf(yv.x, yv.x, y2); y2 = fmaf(yv.y, yv.y, y2);
            y2 = fmaf(yv.z, yv.z, y2); y2 = fmaf(yv.w, yv.w, y2);
        }
        d2 += __shfl_xor(d2, 1, 64); d2 += __shfl_xor(d2, 2, 64);
        y2 += __shfl_xor(y2, 1, 64); y2 += __shfl_xor(y2, 2, 64);
        const float dneg = pdist(x2, y2, d2);
        #pragma unroll
        for (int a = 0; a < Ac; ++a) {
            if (valid[a]) {
                const float h = fmaxf(ma[a] - dneg, 0.0f);
                hg[a] += (row > lt[a]) ? h : 0.0f;
            }
        }
    }

    // sum across the 16 row-groups (values uniform within each quad)
    #pragma unroll
    for (int a = 0; a < Ac; ++a) {
        if (m[a]) {   // wave-uniform
            float v = hg[a];
            v += __shfl_xor(v, 4, 64);
            v += __shfl_xor(v, 8, 64);
            v += __shfl_xor(v, 16, 64);
            v += __shfl_xor(v, 32, 64);
            if (lane == 0) {
                wneg[(size_t)(b * Ac + a) * CHUNKS + c] = v;
                if (c == 0)
                    wpos[b * Ac + a] = valid[a] ? (ma[a] - MARGIN) : 0.0f;
            }
        }
    }
}

__global__ __launch_bounds__(256) void reduce_kernel(
    const float* __restrict__ wneg,
    const float* __restrict__ wpos,
    const int*   __restrict__ align_idx,
    const int*   __restrict__ lookahead_p,
    float* __restrict__ out)
{
    const int tid = threadIdx.x;
    const int lk = lookahead_p[0];
    float pn = 0.0f, pv = 0.0f, nn = 0.0f, nc = 0.0f;
    for (int s = tid; s < NSAMP; s += 256) {
        const int lt = align_idx[s * 2 + 1] + lk;
        const bool valid = (lt >= 0) && (lt < Lc);
        float h = 0.0f;
        #pragma unroll
        for (int c = 0; c < CHUNKS; ++c)
            h += wneg[(size_t)s * CHUNKS + c];
        const float cnt = valid ? (float)(Lc - 1 - lt) : 0.0f;
        const float has_neg = (cnt > 0.0f) ? 1.0f : 0.0f;
        nn += (h / fmaxf(cnt, 1.0f)) * has_neg;
        nc += has_neg;
        pn += wpos[s];
        pv += valid ? 1.0f : 0.0f;
    }
    __shared__ float4 sh[256];
    sh[tid] = make_float4(pn, pv, nn, nc);
    __syncthreads();
    for (int off = 128; off > 0; off >>= 1) {
        if (tid < off) {
            sh[tid].x += sh[tid + off].x;
            sh[tid].y += sh[tid + off].y;
            sh[tid].z += sh[tid + off].z;
            sh[tid].w += sh[tid + off].w;
        }
        __syncthreads();
    }
    if (tid == 0) {
        float pos_term = sh[0].x / fmaxf(sh[0].y, 1.0f);
        float neg_term = sh[0].z / fmaxf(sh[0].w, 1.0f);
        out[0] = pos_term + NEG_WEIGHT * neg_term;
    }
}

extern "C" void kernel_launch(void* const* d_in, const int* in_sizes, int n_in,
                              void* d_out, int out_size, void* d_ws, size_t ws_size,
                              hipStream_t stream) {
    const float* h_curr    = (const float*)d_in[0];
    const float* demo_h    = (const float*)d_in[1];
    const int*   align_idx = (const int*)d_in[2];
    const int*   lookahead = (const int*)d_in[3];
    float* out  = (float*)d_out;
    float* wneg = (float*)d_ws;                       // NSAMP*CHUNKS floats
    float* wpos = (float*)d_ws + NSAMP * CHUNKS;      // NSAMP floats

    sample_kernel<<<Bc * Nc * CHUNKS, 64, 0, stream>>>(
        h_curr, demo_h, align_idx, lookahead, wneg, wpos);
    reduce_kernel<<<1, 256, 0, stream>>>(wneg, wpos, align_idx, lookahead, out);
}